// Round 18
// baseline (284.932 us; speedup 1.0000x reference)
//
#include <hip/hip_runtime.h>
#include <hip/hip_bf16.h>

// GraphSAGE 2-layer forward.
//   layer l: h = BN_l( mean_agg(h_in) @ Wl_l^T + h_in @ Wr_l^T + b_l ); ReLU after layer 0.
// Round 1:  CSR gather-mean (killed fp32 atomics; 3354 -> 804us).
// Round 3:  register-tiled fp32 GEMM (804 -> 428us).
// Round 5:  bf16 + mfma_f32_16x16x32_bf16 GEMM, XOR-swizzled LDS (428 -> 334us).
// Round 8:  gather unroll-4 + fused converts (334 -> 305us).
// Round 10: linked-list adjacency replaces CSR build (305 -> 275us; 11 -> 6 dispatches).
// Round 11: int2-packed (src,next) -> one 8B random read per hop (gather < 56us,
//           but convert_build exposed at 57-65us: 800K random atomicExch lines
//           ping-pong across 8 XCD L2s, WRITE_SIZE 43.8MB ~= 800K x 55B).
// Round 17: shard head[] 8x by build-block id & 7. Default blockIdx->XCD mapping
//           is round-robin mod 8, so each shard is touched by ~one XCD only ->
//           atomics stay L2-local, no cross-XCD line ping-pong. Gather walks the
//           8 short chains per node sequentially (same total hops; BW-bound).

#define D 128
#define BM 64
#define NSHARD 8

typedef __attribute__((ext_vector_type(8))) short short8;   // 8 bf16 (4 VGPRs)
typedef __attribute__((ext_vector_type(4))) float f32x4;

__device__ inline uint f2bf(float f) {   // fp32 -> bf16 bits, round-to-nearest-even
    uint u = __float_as_uint(f);
    return (u + 0x7fffu + ((u >> 16) & 1u)) >> 16;
}

// ---------- fused: dtype conversion (x + 4 weights) || sharded list build ----------
// blocks [0, CB): convert; blocks [CB, CB+EB): list build. Independent work.
__global__ __launch_bounds__(256)
void convert_build_kernel(const float* __restrict__ x, ushort* __restrict__ xb, int n4x,
                          const float* __restrict__ w0, const float* __restrict__ w1,
                          const float* __restrict__ w2, const float* __restrict__ w3,
                          ushort* __restrict__ wb, int CB,
                          const int* __restrict__ srcArr, const int* __restrict__ dst,
                          int* __restrict__ head8, int2* __restrict__ nxt_src,
                          int E, int Nn)
{
    if ((int)blockIdx.x < CB) {
        int i = blockIdx.x * 256 + threadIdx.x;
        if (i < n4x) {
            float4 v = reinterpret_cast<const float4*>(x)[i];
            ushort4 o;
            o.x = (ushort)f2bf(v.x);
            o.y = (ushort)f2bf(v.y);
            o.z = (ushort)f2bf(v.z);
            o.w = (ushort)f2bf(v.w);
            reinterpret_cast<ushort4*>(xb)[i] = o;
        } else {
            int j = i - n4x;                 // 0..16383: 4 matrices x 4096 float4
            if (j < 16384) {
                const float* w = (j < 8192) ? ((j < 4096) ? w0 : w1)
                                            : ((j < 12288) ? w2 : w3);
                float4 v = reinterpret_cast<const float4*>(w)[j & 4095];
                ushort4 o;
                o.x = (ushort)f2bf(v.x);
                o.y = (ushort)f2bf(v.y);
                o.z = (ushort)f2bf(v.z);
                o.w = (ushort)f2bf(v.w);
                reinterpret_cast<ushort4*>(wb)[j] = o;   // 4 contiguous 128x128 bf16
            }
        }
    } else {
        const int bb = (int)blockIdx.x - CB;           // build-block id
        int e = bb * 256 + threadIdx.x;
        if (e < E) {
            int s = srcArr[e];                         // coalesced
            int d = dst[e];                            // coalesced
            const int shard = bb & (NSHARD - 1);       // ~= this block's XCD
            int old = atomicExch(&head8[shard * Nn + d], e);   // XCD-local line
            nxt_src[e] = make_int2(s, old);            // coalesced 8B write
        }
    }
}

// ---------- gather-mean via 8-shard list walk: 4 nodes/wave, 16 lanes/node ----------
// Per hop: ONE random 8B read {src, next}. 8 short chains per node (avg deg/8 = 2
// hops each) walked sequentially; feature row loads (16 lanes x 16B) are the
// BW-bound part. Degree counted inline.
__global__ __launch_bounds__(256)
void gather_list_kernel(const ushort* __restrict__ xb, const int* __restrict__ head8,
                        const int2* __restrict__ nxt_src,
                        ushort* __restrict__ agg, int Nn)
{
    const int gtid = blockIdx.x * 256 + threadIdx.x;
    const int wave = gtid >> 6;
    const int lane = threadIdx.x & 63;
    const int grp  = lane >> 4;          // 0..3 : node within wave
    const int gl   = lane & 15;          // lane within group: 8 bf16 columns
    const int node = wave * 4 + grp;
    if (node >= Nn) return;

    float acc[8] = {0.f, 0.f, 0.f, 0.f, 0.f, 0.f, 0.f, 0.f};
    int cnt = 0;
#pragma unroll
    for (int sh = 0; sh < NSHARD; ++sh) {
        int e = head8[sh * Nn + node];   // uniform within group -> broadcast load
        while (__any(e >= 0)) {
            if (e >= 0) {
                int2 p = nxt_src[e];     // one 8B random read: {src, next}
                short8 v = *reinterpret_cast<const short8*>(xb + (size_t)p.x * D + gl * 8);
#pragma unroll
                for (int j = 0; j < 8; ++j)
                    acc[j] += __uint_as_float(((uint)(ushort)v[j]) << 16);
                ++cnt;
                e = p.y;
            }
        }
    }
    const float sc = 1.0f / fmaxf((float)cnt, 1.0f);
    uint o[4];
#pragma unroll
    for (int j = 0; j < 4; ++j)
        o[j] = f2bf(acc[2 * j] * sc) | (f2bf(acc[2 * j + 1] * sc) << 16);
    *reinterpret_cast<uint4*>(agg + (size_t)node * D + gl * 8) =
        make_uint4(o[0], o[1], o[2], o[3]);
}

// ---------- MFMA GEMM + BN epilogue (unchanged from verified round 5) ----------
// out[n,j] = BN( sum_k aggb[n,k]*Wl[j,k] + selfb[n,k]*Wr[j,k] + b[j] ), opt ReLU.
// Block: 64 rows x 128 cols, 4 waves in 2x2 grid (wave: 32 rows x 64 cols).
// A(64x128) and W(128x128) staged bf16 in LDS, row-linear with ci^=(row&7) XOR
// swizzle (write and read) -> conflict-free ds_read_b128 fragments.
// mfma_f32_16x16x32_bf16: A/B frag: lane l holds row/col (l&15), k=(l>>4)*8+j;
// C/D: col=lane&15, row=(lane>>4)*4+reg  [m89-verified mapping].
__global__ __launch_bounds__(256)
void mfma_gemm_bn_kernel(const ushort* __restrict__ aggb,
                         const ushort* __restrict__ selfb,
                         const ushort* __restrict__ Wlb, const ushort* __restrict__ Wrb,
                         const float* __restrict__ bias,
                         const float* __restrict__ gamma, const float* __restrict__ beta,
                         const float* __restrict__ rmean, const float* __restrict__ rvar,
                         void* __restrict__ outp, int relu, int out_bf16, int Nn)
{
    __shared__ ushort Alds[BM * D];      // 16 KB
    __shared__ ushort Blds[D * D];       // 32 KB

    const int tid = threadIdx.x;
    const int lane = tid & 63;
    const int wid = tid >> 6;
    const int wr = wid >> 1;             // wave row-half (0/1): rows wr*32..+31
    const int wc = wid & 1;              // wave col-half (0/1): cols wc*64..+63
    const int nb = blockIdx.x * BM;

    const f32x4 z = {0.f, 0.f, 0.f, 0.f};
    f32x4 acc[2][4];
#pragma unroll
    for (int bi = 0; bi < 2; ++bi)
#pragma unroll
        for (int ti = 0; ti < 4; ++ti) acc[bi][ti] = z;

    for (int pass = 0; pass < 2; ++pass) {
        const ushort* __restrict__ A = pass ? selfb : aggb;
        const ushort* __restrict__ W = pass ? Wrb : Wlb;
        if (pass) __syncthreads();       // pass-0 reads done before restaging

        // stage A: 64 rows x 16 chunks(16B); swizzled LDS write
#pragma unroll
        for (int it = 0; it < 4; ++it) {
            int c = it * 256 + tid;
            int row = c >> 4, ci = c & 15;
            int gn = nb + row;
            short8 v = {};
            if (gn < Nn) v = *reinterpret_cast<const short8*>(A + (size_t)gn * D + ci * 8);
            *reinterpret_cast<short8*>(&Alds[row * D + ((ci ^ (row & 7)) * 8)]) = v;
        }
        // stage W: 128 rows x 16 chunks
#pragma unroll
        for (int it = 0; it < 8; ++it) {
            int c = it * 256 + tid;
            int j = c >> 4, ci = c & 15;
            short8 w = *reinterpret_cast<const short8*>(W + j * D + ci * 8);
            *reinterpret_cast<short8*>(&Blds[j * D + ((ci ^ (j & 7)) * 8)]) = w;
        }
        __syncthreads();

#pragma unroll
        for (int ks = 0; ks < 4; ++ks) {             // K chunks of 32
            const int kg = lane >> 4;                // k-group 0..3
            const int ci = ks * 4 + kg;
            short8 af[2], bfr[4];
#pragma unroll
            for (int bi = 0; bi < 2; ++bi) {
                int row = wr * 32 + bi * 16 + (lane & 15);
                af[bi] = *reinterpret_cast<const short8*>(
                    &Alds[row * D + ((ci ^ (row & 7)) * 8)]);
            }
#pragma unroll
            for (int ti = 0; ti < 4; ++ti) {
                int j = wc * 64 + ti * 16 + (lane & 15);
                bfr[ti] = *reinterpret_cast<const short8*>(
                    &Blds[j * D + ((ci ^ (j & 7)) * 8)]);
            }
#pragma unroll
            for (int bi = 0; bi < 2; ++bi)
#pragma unroll
                for (int ti = 0; ti < 4; ++ti)
                    acc[bi][ti] = __builtin_amdgcn_mfma_f32_16x16x32_bf16(
                        af[bi], bfr[ti], acc[bi][ti], 0, 0, 0);
        }
    }

    // epilogue: bias + BN fused per-column scale/shift; optional ReLU
#pragma unroll
    for (int ti = 0; ti < 4; ++ti) {
        int col = wc * 64 + ti * 16 + (lane & 15);
        float sc = gamma[col] * rsqrtf(rvar[col] + 1e-5f);
        float sh = bias[col] * sc + beta[col] - rmean[col] * sc;
#pragma unroll
        for (int bi = 0; bi < 2; ++bi) {
#pragma unroll
            for (int r = 0; r < 4; ++r) {
                int row = nb + wr * 32 + bi * 16 + (lane >> 4) * 4 + r;
                if (row < Nn) {
                    float v = acc[bi][ti][r] * sc + sh;
                    if (relu) v = fmaxf(v, 0.f);
                    if (out_bf16)
                        ((ushort*)outp)[(size_t)row * D + col] = (ushort)f2bf(v);
                    else
                        ((float*)outp)[(size_t)row * D + col] = v;
                }
            }
        }
    }
}

extern "C" void kernel_launch(void* const* d_in, const int* in_sizes, int n_in,
                              void* d_out, int out_size, void* d_ws, size_t ws_size,
                              hipStream_t stream)
{
    const float* x   = (const float*)d_in[0];
    const int*   ei  = (const int*)d_in[1];
    const float* Wl0 = (const float*)d_in[2];
    const float* Wr0 = (const float*)d_in[3];
    const float* b0  = (const float*)d_in[4];
    const float* g0  = (const float*)d_in[5];
    const float* be0 = (const float*)d_in[6];
    const float* rm0 = (const float*)d_in[7];
    const float* rv0 = (const float*)d_in[8];
    const float* Wl1 = (const float*)d_in[9];
    const float* Wr1 = (const float*)d_in[10];
    const float* b1  = (const float*)d_in[11];
    const float* g1  = (const float*)d_in[12];
    const float* be1 = (const float*)d_in[13];
    const float* rm1 = (const float*)d_in[14];
    const float* rv1 = (const float*)d_in[15];

    const int N = in_sizes[0] / D;
    const int E = in_sizes[1] / 2;
    const int* src = ei;
    const int* dst = ei + E;

    // workspace: xb u16[N*D] | aggb u16[N*D] | h0b u16[N*D] | wbf u16[4*16384] |
    //            head8 i[8N] | nxt_src int2[E]
    ushort* xb   = (ushort*)d_ws;
    ushort* aggb = xb + (size_t)N * D;
    ushort* h0b  = aggb + (size_t)N * D;
    ushort* wbf  = h0b + (size_t)N * D;
    int*    head8 = (int*)(wbf + 4 * 16384);
    int2*   nxt_src = (int2*)(head8 + NSHARD * N);

    ushort* wl0b = wbf;
    ushort* wr0b = wbf + 16384;
    ushort* wl1b = wbf + 2 * 16384;
    ushort* wr1b = wbf + 3 * 16384;

    float* out = (float*)d_out;

    const int n4x = N * D / 4;
    const int CB  = (n4x + 16384 + 255) / 256;       // convert blocks
    const int EB  = (E + 255) / 256;                 // build blocks
    const int gemm_blocks = (N + BM - 1) / BM;
    const int gather_blocks = ((N + 3) / 4 * 64 + 255) / 256;   // 4 nodes per wave

    // ---- head8 = -1; then [convert || sharded list-build] in one kernel ----
    hipMemsetAsync(head8, 0xFF, sizeof(int) * NSHARD * N, stream);
    convert_build_kernel<<<CB + EB, 256, 0, stream>>>(
        x, xb, n4x, Wl0, Wr0, Wl1, Wr1, wbf, CB, src, dst, head8, nxt_src, E, N);

    // ---- layer 0 ----
    gather_list_kernel<<<gather_blocks, 256, 0, stream>>>(xb, head8, nxt_src, aggb, N);
    mfma_gemm_bn_kernel<<<gemm_blocks, 256, 0, stream>>>(
        aggb, xb, wl0b, wr0b, b0, g0, be0, rm0, rv0, h0b, 1, 1, N);
    // ---- layer 1 ----
    gather_list_kernel<<<gather_blocks, 256, 0, stream>>>(h0b, head8, nxt_src, aggb, N);
    mfma_gemm_bn_kernel<<<gemm_blocks, 256, 0, stream>>>(
        aggb, h0b, wl1b, wr1b, b1, g1, be1, rm1, rv1, out, 0, 0, N);
}